// Round 23
// baseline (312.958 us; speedup 1.0000x reference)
//
#include <hip/hip_runtime.h>

// ---------------------------------------------------------------------------
// GNN compound encoder, MI355X (gfx950) — round 23 (= round 21, known-good)
// Round 22's degree-sort perm FAILED post-timing revalidation (absmax 12.9,
// timing-dependent, same signature as round 17's LDS edge-staging failure).
// Both unexplained -> reverted per rigor discipline. This is the verified
// 312us / absmax 0.25 configuration:
//  - conv1 = atom-count rows (k_counts, LDS histogram) + MFMA GEMM w/ exact
//    f32 T1[x] base; M1 = W1a@emb^T table (K=128)
//  - conv2 + final = bf16 MFMA GEMMs (fragment-baked W, BN fold, stats
//    partials, LDS-reduced fused graph-max)
//  - gathers: 2 threads/node, 40/48-feat f32 reg accumulators, 16B loads
//  - CSR: XCD-range-partitioned fill (int slots), parallel BN reduce
// ---------------------------------------------------------------------------

#define NN 100000
#define NE 800000
#define NC 20000
#define NGE 320000
#define NG 256

typedef __attribute__((ext_vector_type(8))) short bf16x8;
typedef __attribute__((ext_vector_type(4))) float f32x4;

__device__ __forceinline__ ushort f2bf(float x) {  // RNE f32 -> bf16
  unsigned u = __float_as_uint(x);
  u = (u + 0x7FFFu + ((u >> 16) & 1u)) >> 16;
  return (ushort)u;
}
__device__ __forceinline__ float bf2f(ushort h) {
  return __uint_as_float(((unsigned)h) << 16);
}
__device__ __forceinline__ float bflo(unsigned w) {
  return __uint_as_float(w << 16);
}
__device__ __forceinline__ float bfhi(unsigned w) {
  return __uint_as_float(w & 0xFFFF0000u);
}

// --------------------------- CSR build -------------------------------------
__global__ void k_count(const int* __restrict__ ei, int nE,
                        int* __restrict__ deg) {
  for (int e = blockIdx.x * blockDim.x + threadIdx.x; e < nE;
       e += gridDim.x * blockDim.x)
    atomicAdd(&deg[ei[nE + e]], 1);
}

__global__ __launch_bounds__(256) void k_scan_block(
    const int* __restrict__ deg, int n, int* __restrict__ start,
    int* __restrict__ bsum) {
  __shared__ int sh[256];
  int base = blockIdx.x * 1024 + threadIdx.x * 4;
  int v0 = (base + 0 < n) ? deg[base + 0] : 0;
  int v1 = (base + 1 < n) ? deg[base + 1] : 0;
  int v2 = (base + 2 < n) ? deg[base + 2] : 0;
  int v3 = (base + 3 < n) ? deg[base + 3] : 0;
  sh[threadIdx.x] = v0 + v1 + v2 + v3;
  __syncthreads();
  for (int off = 1; off < 256; off <<= 1) {
    int t = (threadIdx.x >= off) ? sh[threadIdx.x - off] : 0;
    __syncthreads();
    sh[threadIdx.x] += t;
    __syncthreads();
  }
  int run = (threadIdx.x == 0) ? 0 : sh[threadIdx.x - 1];
  if (base + 0 < n) start[base + 0] = run;
  run += v0;
  if (base + 1 < n) start[base + 1] = run;
  run += v1;
  if (base + 2 < n) start[base + 2] = run;
  run += v2;
  if (base + 3 < n) start[base + 3] = run;
  if (threadIdx.x == 255) bsum[blockIdx.x] = sh[255];
}

__global__ void k_scan_mid(int* __restrict__ bsum, int nb) {
  if (blockIdx.x == 0 && threadIdx.x == 0) {
    int run = 0;
    for (int i = 0; i < nb; ++i) {
      int t = bsum[i];
      bsum[i] = run;
      run += t;
    }
  }
}

__global__ void k_scan_add(int* __restrict__ start, const int* __restrict__ bsum,
                           int n) {
  int i = blockIdx.x * blockDim.x + threadIdx.x;
  if (i < n) start[i] += bsum[i >> 10];
}

// ---- XCD-range-partitioned fill: block (r,g) commits targets in range r ---
__global__ void k_fill2(const int* __restrict__ ei, int nE,
                        const int* __restrict__ start, int* __restrict__ cur,
                        int* __restrict__ dst, int n) {
  int r = blockIdx.x & 7;
  int g = blockIdx.x >> 3;
  int G = gridDim.x >> 3;
  int chunk = (nE + G - 1) / G;
  int e0 = g * chunk;
  int e1 = e0 + chunk; if (e1 > nE) e1 = nE;
  for (int e = e0 + threadIdx.x; e < e1; e += blockDim.x) {
    int t = ei[nE + e];
    if ((t * 8) / n == r) {
      int slot = start[t] + atomicAdd(&cur[t], 1);
      dst[slot] = ei[e];
    }
  }
}

// ---- conv1 tables: M1t[f][v] f32 = W1a@emb^T transposed; T1[v][f] f32 -----
__global__ void k_prep1(const float* __restrict__ w1,
                        const float* __restrict__ b1,
                        const float* __restrict__ emb,
                        float* __restrict__ M1t, float* __restrict__ T1) {
  int idx = blockIdx.x * 256 + threadIdx.x;
  if (idx < 128 * 80) {
    int v = idx / 80, f = idx - v * 80;
    const float* er = emb + (size_t)v * 64;
    const float* wa = w1 + (size_t)f * 128;
    const float* wb = wa + 64;
    float sa = 0.f, sb = b1[f];
    for (int k = 0; k < 64; ++k) {
      sa = fmaf(wa[k], er[k], sa);
      sb = fmaf(wb[k], er[k], sb);
    }
    T1[idx] = sb;
    M1t[(size_t)f * 128 + v] = sa;
  }
}

// ---- adjusted bias: badj[f] = b[f] + sum_k W[f][D1+k]*shift[k] ------------
template <int F, int K, int D1>
__global__ void k_badj(const float* __restrict__ W, const float* __restrict__ b,
                       const float* __restrict__ sc, float* __restrict__ badj) {
  int f = blockIdx.x * blockDim.x + threadIdx.x;
  if (f < F) {
    float s = b[f];
    for (int k = 0; k < K - D1; ++k)
      s += W[(size_t)f * K + D1 + k] * sc[(K - D1) + k];
    badj[f] = s;
  }
}

// -------- W -> fragment-ordered bf16 (optional BN-scale fold k>=D1) --------
template <int KB, int F, int WS, int D1, bool AFFW>
__global__ void k_wfrag(const float* __restrict__ W, const float* __restrict__ scW,
                        ushort* __restrict__ WF) {
  int idx = blockIdx.x * blockDim.x + threadIdx.x;
  constexpr int NFT = F / 16;
  int total = (KB / 32) * NFT * 64;
  if (idx >= total) return;
  int lane = idx & 63, frag = idx >> 6;
  int ftile = frag % NFT, ktile = frag / NFT;
  int f = ftile * 16 + (lane & 15);
  int k0 = ktile * 32 + ((lane >> 4) << 3);
  ushort v[8];
#pragma unroll
  for (int j = 0; j < 8; ++j) {
    int k = k0 + j;
    float w = W[(size_t)f * WS + k];
    if (AFFW && k >= D1) w *= scW[k - D1];
    v[j] = f2bf(w);
  }
  ushort* p = WF + (size_t)idx * 8;
  *reinterpret_cast<ushort4*>(p) = make_ushort4(v[0], v[1], v[2], v[3]);
  *reinterpret_cast<ushort4*>(p + 4) = make_ushort4(v[4], v[5], v[6], v[7]);
}

// ---- atom-count rows: Z1c[nd][128] bf16, counts of neighbor atom ids ------
__global__ __launch_bounds__(256) void k_counts(
    const int* __restrict__ x, const int* __restrict__ start,
    const int* __restrict__ deg, const int* __restrict__ srcl,
    ushort* __restrict__ Z1c, int n) {
  __shared__ unsigned cnt[64][128];
  const int t = threadIdx.x;
  const int nd0 = blockIdx.x * 64;
  for (int i = t; i < 8192; i += 256)
    reinterpret_cast<unsigned*>(cnt)[i] = 0u;
  __syncthreads();
  const int ndl = t >> 2;        // 0..63
  const int j0 = t & 3;
  const int nd = nd0 + ndl;
  if (nd < n) {
    int s0 = start[nd], dg = deg[nd];
    for (int j = j0; j < dg; j += 4) {
      int v = x[srcl[s0 + j]];
      atomicAdd(&cnt[ndl][v], 1u);
    }
  }
  __syncthreads();
  for (int i = t; i < 4096; i += 256) {
    int ndw = i >> 6, vp = i & 63;
    unsigned lo = f2bf((float)cnt[ndw][2 * vp]);
    unsigned hi = f2bf((float)cnt[ndw][2 * vp + 1]);
    int g = nd0 + ndw;
    if (g < n)
      reinterpret_cast<unsigned*>(Z1c + (size_t)g * 128)[vp] = lo | (hi << 16);
  }
}

// -------- conv2 gather: 2 threads/node, 40 feats each, 16B row loads -------
__global__ __launch_bounds__(256) void k_gather_h1_bf(
    const ushort* __restrict__ Z2r, const int* __restrict__ start,
    const int* __restrict__ deg, const int* __restrict__ srcl,
    const float* __restrict__ sc, ushort* __restrict__ Z2w, int n) {
  int idx = blockIdx.x * blockDim.x + threadIdx.x;
  int nd = idx >> 1, half = idx & 1;
  if (nd >= n) return;
  const int f0 = half * 40;
  float acc[40];
#pragma unroll
  for (int i = 0; i < 40; ++i) acc[i] = 0.f;
  int s0 = start[nd], dg = deg[nd];
  for (int j = 0; j < dg; ++j) {
    int s = srcl[s0 + j];
    const uint4* rp = reinterpret_cast<const uint4*>(
        Z2r + (size_t)s * 160 + 80 + f0);
#pragma unroll
    for (int q = 0; q < 5; ++q) {
      uint4 w = rp[q];
      acc[8 * q + 0] += bflo(w.x); acc[8 * q + 1] += bfhi(w.x);
      acc[8 * q + 2] += bflo(w.y); acc[8 * q + 3] += bfhi(w.y);
      acc[8 * q + 4] += bflo(w.z); acc[8 * q + 5] += bfhi(w.z);
      acc[8 * q + 6] += bflo(w.w); acc[8 * q + 7] += bfhi(w.w);
    }
  }
  float fd = (float)dg;
  uint4* op = reinterpret_cast<uint4*>(Z2w + (size_t)nd * 160 + f0);
#pragma unroll
  for (int q = 0; q < 5; ++q) {
    unsigned pk[4];
#pragma unroll
    for (int p = 0; p < 4; ++p) {
      int f = f0 + 8 * q + 2 * p;
      float v0 = fmaf(acc[8 * q + 2 * p + 0], sc[f + 0], fd * sc[80 + f + 0]);
      float v1 = fmaf(acc[8 * q + 2 * p + 1], sc[f + 1], fd * sc[80 + f + 1]);
      pk[p] = (unsigned)f2bf(v0) | ((unsigned)f2bf(v1) << 16);
    }
    op[q] = make_uint4(pk[0], pk[1], pk[2], pk[3]);
  }
}

// -------- cluster gather: 2 threads/cluster, 48 feats each, 16B loads ------
__global__ __launch_bounds__(256) void k_gather_y_bf(
    const ushort* __restrict__ Z3r, const int* __restrict__ start,
    const int* __restrict__ deg, const int* __restrict__ srcl,
    ushort* __restrict__ Z3w, int n) {
  int idx = blockIdx.x * blockDim.x + threadIdx.x;
  int c = idx >> 1, half = idx & 1;
  if (c >= n) return;
  const int f0 = half * 48;
  float acc[48];
#pragma unroll
  for (int i = 0; i < 48; ++i) acc[i] = 0.f;
  int s0 = start[c], dg = deg[c];
  for (int j = 0; j < dg; ++j) {
    int s = srcl[s0 + j];
    const uint4* rp = reinterpret_cast<const uint4*>(
        Z3r + (size_t)s * 192 + 96 + f0);
#pragma unroll
    for (int q = 0; q < 6; ++q) {
      uint4 w = rp[q];
      acc[8 * q + 0] += bflo(w.x); acc[8 * q + 1] += bfhi(w.x);
      acc[8 * q + 2] += bflo(w.y); acc[8 * q + 3] += bfhi(w.y);
      acc[8 * q + 4] += bflo(w.z); acc[8 * q + 5] += bfhi(w.z);
      acc[8 * q + 6] += bflo(w.w); acc[8 * q + 7] += bfhi(w.w);
    }
  }
  uint4* op = reinterpret_cast<uint4*>(Z3w + (size_t)c * 192 + f0);
#pragma unroll
  for (int q = 0; q < 6; ++q) {
    unsigned pk[4];
#pragma unroll
    for (int p = 0; p < 4; ++p) {
      pk[p] = (unsigned)f2bf(acc[8 * q + 2 * p + 0]) |
              ((unsigned)f2bf(acc[8 * q + 2 * p + 1]) << 16);
    }
    op[q] = make_uint4(pk[0], pk[1], pk[2], pk[3]);
  }
}

// ---- cluster max (5 rows, bf16 in) + BN2 affine (scale>0) -> Z3 y-half ----
__global__ void k_cluster_max_bf(const ushort* __restrict__ h2,
                                 const float* __restrict__ sc,
                                 ushort* __restrict__ Z3, int C) {
  int total = C * 96;
  for (int idx = blockIdx.x * blockDim.x + threadIdx.x; idx < total;
       idx += gridDim.x * blockDim.x) {
    int c = idx / 96;
    int d = idx - c * 96;
    const ushort* p = h2 + (size_t)(c * 5) * 96 + d;
    float m = bf2f(p[0]);
    m = fmaxf(m, bf2f(p[96]));
    m = fmaxf(m, bf2f(p[192]));
    m = fmaxf(m, bf2f(p[288]));
    m = fmaxf(m, bf2f(p[384]));
    m = fmaf(m, sc[d], sc[96 + d]);  // scale>0: affine commutes with max
    Z3[(size_t)c * 192 + 96 + d] = f2bf(m);
  }
}

__global__ void k_ybatch(const int* __restrict__ batch, int* __restrict__ yb,
                         int C) {
  for (int c = blockIdx.x * blockDim.x + threadIdx.x; c < C;
       c += gridDim.x * blockDim.x) {
    int m = batch[c * 5];
    m = max(m, batch[c * 5 + 1]);
    m = max(m, batch[c * 5 + 2]);
    m = max(m, batch[c * 5 + 3]);
    m = max(m, batch[c * 5 + 4]);
    yb[c] = m;
  }
}

// ---- BN partial reduce + finalize: one block PER FEATURE ------------------
template <int D>
__global__ __launch_bounds__(256) void k_bn_reduce_final(
    const float* __restrict__ sp, int nblk, const float* __restrict__ g,
    const float* __restrict__ be, int n, float* __restrict__ sc) {
  constexpr int TD = 2 * D;
  __shared__ double rs[256], rq[256];
  const int d = blockIdx.x;
  const int t = threadIdx.x;
  double s = 0.0, q = 0.0;
  for (int b = t; b < nblk; b += 256) {
    s += (double)sp[(size_t)b * TD + d];
    q += (double)sp[(size_t)b * TD + D + d];
  }
  rs[t] = s;
  rq[t] = q;
  __syncthreads();
  for (int off = 128; off > 0; off >>= 1) {
    if (t < off) {
      rs[t] += rs[t + off];
      rq[t] += rq[t + off];
    }
    __syncthreads();
  }
  if (t == 0) {
    double mean = rs[0] / n;
    double var = rq[0] / n - mean * mean;
    float scale = g[d] * rsqrtf((float)var + 1e-5f);
    sc[d] = scale;
    sc[D + d] = be[d] - (float)mean * scale;
  }
}

// ------------------- MFMA GEMM epilogue (one 16-row tile) ------------------
template <int NT, int FGLOB, bool T1M, bool STATS, bool OUTBF, bool GMAX>
__device__ __forceinline__ void epilogue(
    const f32x4 (&acc)[NT], int r0base, int lane, int fbase, int rows,
    const float* __restrict__ bias, const int* __restrict__ xid,
    const float* __restrict__ t1, ushort* __restrict__ outBF, int ostride,
    int ooff, const int* __restrict__ yb, int g_base, unsigned* gred,
    float* sred) {
  const int r0 = r0base + ((lane >> 4) << 2);
  bool val[4];
  int gb[4], xv[4];
#pragma unroll
  for (int r = 0; r < 4; ++r) {
    int g = r0 + r;
    val[r] = g < rows;
    if (GMAX) gb[r] = yb[val[r] ? g : 0];
    if (T1M) xv[r] = xid[val[r] ? g : 0];
  }
#pragma unroll
  for (int n = 0; n < NT; ++n) {
    const int fl = n * 16 + (lane & 15);
    const int f = fbase + fl;
    float bb = T1M ? 0.f : bias[f];
    float s = 0.f, q = 0.f;
#pragma unroll
    for (int r = 0; r < 4; ++r) {
      if (val[r]) {
        float v = acc[n][r] +
                  (T1M ? t1[(size_t)xv[r] * FGLOB + f] : bb);
        v = v > 0.f ? v : 0.f;
        int g = r0 + r;
        if (OUTBF) outBF[(size_t)g * ostride + ooff + f] = f2bf(v);
        if (GMAX) {
          if (v > 0.f)
            atomicMax(&gred[(gb[r] - g_base) * (NT * 16) + fl],
                      __float_as_uint(v));
        }
        if (STATS) {
          s += v;
          q += v * v;
        }
      }
    }
    if (STATS) {
      s += __shfl_xor(s, 16); q += __shfl_xor(q, 16);
      s += __shfl_xor(s, 32); q += __shfl_xor(q, 32);
      if (lane < 16) {
        atomicAdd(&sred[fl], s);
        atomicAdd(&sred[FGLOB + fl], q);
      }
    }
  }
}

// ------------------- MFMA GEMM on bf16 row-major Z -------------------------
// 128 rows/block: 4 waves x 2 tiles of 16 rows (+0 / +64). Layouts per r12.
template <int KB, int NT, int FGLOB, bool T1M, bool STATS, bool OUTBF,
          bool GMAX>
__global__ __launch_bounds__(256) void k_gemm_mfma(
    const ushort* __restrict__ Z, const ushort* __restrict__ WF,
    const float* __restrict__ bias, const int* __restrict__ xid,
    const float* __restrict__ t1, ushort* __restrict__ outBF, int ostride,
    int ooff, const int* __restrict__ yb, float* __restrict__ gout,
    float* __restrict__ stpart, int rows) {
  constexpr int KSTEPS = KB / 32;
  constexpr int NFT = FGLOB / 16;
  const int t = threadIdx.x;
  const int lane = t & 63;
  const int wv = t >> 6;
  const int rowA = blockIdx.x * 128 + wv * 16;
  const int rowB = rowA + 64;
  const int fbase = blockIdx.y * (NT * 16);
  const int ft0 = fbase >> 4;

  __shared__ float sred[STATS ? 2 * FGLOB : 1];
  __shared__ unsigned gred[GMAX ? 4 * NT * 16 : 1];
  if (STATS)
    for (int i = t; i < 2 * FGLOB; i += 256) sred[i] = 0.f;
  if (GMAX)
    for (int i = t; i < 4 * NT * 16; i += 256) gred[i] = 0u;
  if (STATS || GMAX) __syncthreads();

  int arA = rowA + (lane & 15); if (arA >= rows) arA = rows - 1;
  int arB = rowB + (lane & 15); if (arB >= rows) arB = rows - 1;
  const ushort* apA = Z + (size_t)arA * KB + ((lane >> 4) << 3);
  const ushort* apB = Z + (size_t)arB * KB + ((lane >> 4) << 3);

  f32x4 accA[NT], accB[NT];
#pragma unroll
  for (int n = 0; n < NT; ++n) {
    accA[n] = (f32x4){0.f, 0.f, 0.f, 0.f};
    accB[n] = (f32x4){0.f, 0.f, 0.f, 0.f};
  }

#pragma unroll
  for (int ks = 0; ks < KSTEPS; ++ks) {
    bf16x8 afA = *reinterpret_cast<const bf16x8*>(apA + ks * 32);
    bf16x8 afB = *reinterpret_cast<const bf16x8*>(apB + ks * 32);
#pragma unroll
    for (int n = 0; n < NT; ++n) {
      bf16x8 bf = *reinterpret_cast<const bf16x8*>(
          WF + (((size_t)((ks * NFT + ft0 + n) * 64 + lane)) << 3));
      accA[n] = __builtin_amdgcn_mfma_f32_16x16x32_bf16(afA, bf, accA[n], 0, 0, 0);
      accB[n] = __builtin_amdgcn_mfma_f32_16x16x32_bf16(afB, bf, accB[n], 0, 0, 0);
    }
  }

  int g_base = 0, g_last = 0;
  if (GMAX) {
    int cb = blockIdx.x * 128;       if (cb >= rows) cb = rows - 1;
    int ce = blockIdx.x * 128 + 127; if (ce >= rows) ce = rows - 1;
    g_base = yb[cb];
    g_last = yb[ce];
  }

  epilogue<NT, FGLOB, T1M, STATS, OUTBF, GMAX>(
      accA, rowA, lane, fbase, rows, bias, xid, t1, outBF, ostride, ooff, yb,
      g_base, gred, sred);
  epilogue<NT, FGLOB, T1M, STATS, OUTBF, GMAX>(
      accB, rowB, lane, fbase, rows, bias, xid, t1, outBF, ostride, ooff, yb,
      g_base, gred, sred);

  if (STATS) {
    __syncthreads();
    for (int i = t; i < 2 * FGLOB; i += 256)
      stpart[(size_t)blockIdx.x * (2 * FGLOB) + i] = sred[i];
  }
  if (GMAX) {
    __syncthreads();
    for (int i = t; i < 4 * NT * 16; i += 256) {
      int s = i / (NT * 16), fl = i - s * (NT * 16);
      if (g_base + s <= g_last) {
        unsigned v = gred[i];
        if (v)
          atomicMax((unsigned*)&gout[(size_t)(g_base + s) * 256 + fbase + fl],
                    v);
      }
    }
  }
}

// ---------------------------------------------------------------------------
extern "C" void kernel_launch(void* const* d_in, const int* in_sizes, int n_in,
                              void* d_out, int out_size, void* d_ws,
                              size_t ws_size, hipStream_t stream) {
  const int* x = (const int*)d_in[0];
  const int* ei = (const int*)d_in[1];          // [2][NE]
  const int* batch = (const int*)d_in[2];
  // d_in[3] = cluster_index (contiguous arange//5; structure used directly)
  const int* gei = (const int*)d_in[4];         // [2][NGE]
  const float* emb = (const float*)d_in[5];
  const float* w1 = (const float*)d_in[6];
  const float* b1 = (const float*)d_in[7];
  const float* g1 = (const float*)d_in[8];
  const float* be1 = (const float*)d_in[9];
  const float* w2 = (const float*)d_in[10];
  const float* b2 = (const float*)d_in[11];
  const float* g2 = (const float*)d_in[12];
  const float* be2 = (const float*)d_in[13];
  const float* wm = (const float*)d_in[14];
  const float* bm = (const float*)d_in[15];
  float* out = (float*)d_out;

  // ---- workspace overlay -----------------------------------------------
  ushort* Z2 = (ushort*)d_ws;               // [100032][160] (0-79 agg2, 80-159 h1)
  ushort* Z3 = Z2 + (size_t)100032 * 160;   // [20032][192]  (0-95 aggc, 96-191 y)
  ushort* h2b = Z3 + (size_t)20032 * 192;   // [100032][96]  bf16 h2
  ushort* Z1c = h2b + (size_t)100032 * 96;  // [100032][128] bf16 atom counts
  ushort* wf1 = Z1c + (size_t)100032 * 128; // 4*5*64*8 = 10240
  ushort* wf2 = wf1 + 10240;                // 15360
  ushort* wfm = wf2 + 15360;                // 49152
  float* M1t = (float*)(wfm + 49152);       // [80][128] f32
  float* T1v = M1t + 10240;                 // [128][80] f32
  float* badj2 = T1v + 10240;               // 96 (pad 128)
  float* sc1 = badj2 + 128;                 // 160 (pad 192)
  float* sc2 = sc1 + 192;                   // 192
  float* stpart = sc2 + 192;                // 1024*192 floats
  int* ip = (int*)(stpart + 196608);
  int* nd_deg = ip;            ip += NN;
  int* nd_start = ip;          ip += NN;
  int* nd_cur = ip;            ip += NN;
  int* nd_src = ip;            ip += NE;
  int* cl_deg = ip;            ip += NC;
  int* cl_start = ip;          ip += NC;
  int* cl_cur = ip;            ip += NC;
  int* cl_src = ip;            ip += NGE;
  int* yb = ip;                ip += NC;
  int* bsum = ip;              ip += 128;

  const int BLK = 256;
  const int GB = (NN + 127) / 128;          // 782 GEMM blocks (node layers)
  const int CB = (NN + 63) / 64;            // 1563 counts blocks

  // ---- node-graph CSR (int slots: src)
  hipMemsetAsync(nd_deg, 0, NN * 4, stream);
  hipMemsetAsync(nd_cur, 0, NN * 4, stream);
  k_count<<<1024, BLK, 0, stream>>>(ei, NE, nd_deg);
  k_scan_block<<<(NN + 1023) / 1024, BLK, 0, stream>>>(nd_deg, NN, nd_start, bsum);
  k_scan_mid<<<1, 64, 0, stream>>>(bsum, (NN + 1023) / 1024);
  k_scan_add<<<(NN + 255) / 256, BLK, 0, stream>>>(nd_start, bsum, NN);
  k_fill2<<<1024, BLK, 0, stream>>>(ei, NE, nd_start, nd_cur, nd_src, NN);

  // ---- parameter prep: M1t/T1 tables, conv1+final W fragments
  k_prep1<<<40, BLK, 0, stream>>>(w1, b1, emb, M1t, T1v);
  k_wfrag<128, 80, 128, 128, false><<<5, BLK, 0, stream>>>(M1t, nullptr, wf1);
  k_wfrag<192, 256, 192, 96, false><<<24, BLK, 0, stream>>>(wm, nullptr, wfm);

  // ---- conv1: atom-count rows -> MFMA GEMM (T1 base, stats, h1->Z2 strided)
  k_counts<<<CB, BLK, 0, stream>>>(x, nd_start, nd_deg, nd_src, Z1c, NN);
  k_gemm_mfma<128, 5, 80, true, true, true, false>
      <<<dim3(GB, 1), BLK, 0, stream>>>(
          Z1c, wf1, nullptr, x, T1v, Z2, 160, 80, nullptr, nullptr, stpart,
          NN);
  k_bn_reduce_final<80><<<80, 256, 0, stream>>>(stpart, GB, g1, be1, NN, sc1);
  k_badj<96, 160, 80><<<1, 128, 0, stream>>>(w2, b2, sc1, badj2);
  k_wfrag<160, 96, 160, 80, true><<<8, BLK, 0, stream>>>(w2, sc1, wf2);

  // ---- conv2: gather h1 (2 thr/node, affine fold) -> Z2 cols 0-79;
  //      MFMA GEMM -> h2 bf16
  k_gather_h1_bf<<<(NN * 2 + BLK - 1) / BLK, BLK, 0, stream>>>(
      Z2, nd_start, nd_deg, nd_src, sc1, Z2, NN);
  k_gemm_mfma<160, 6, 96, false, true, true, false>
      <<<dim3(GB, 1), BLK, 0, stream>>>(
          Z2, wf2, badj2, nullptr, nullptr, h2b, 96, 0, nullptr, nullptr,
          stpart, NN);
  k_bn_reduce_final<96><<<96, 256, 0, stream>>>(stpart, GB, g2, be2, NN, sc2);

  // ---- cluster pooling: max over 5 rows (bf16) + BN2 affine -> Z3 y-half
  k_cluster_max_bf<<<2048, BLK, 0, stream>>>(h2b, sc2, Z3, NC);
  k_ybatch<<<(NC + BLK - 1) / BLK, BLK, 0, stream>>>(batch, yb, NC);

  // ---- cluster-graph CSR (int slots)
  hipMemsetAsync(cl_deg, 0, NC * 4, stream);
  hipMemsetAsync(cl_cur, 0, NC * 4, stream);
  k_count<<<512, BLK, 0, stream>>>(gei, NGE, cl_deg);
  k_scan_block<<<(NC + 1023) / 1024, BLK, 0, stream>>>(cl_deg, NC, cl_start, bsum);
  k_scan_mid<<<1, 64, 0, stream>>>(bsum, (NC + 1023) / 1024);
  k_scan_add<<<(NC + 255) / 256, BLK, 0, stream>>>(cl_start, bsum, NC);
  k_fill2<<<512, BLK, 0, stream>>>(gei, NGE, cl_start, cl_cur, cl_src, NC);

  // ---- final: gather y (2 thr/cluster) -> Z3 cols 0-95;
  //      MFMA GEMM + fused graph-max
  k_gather_y_bf<<<(NC * 2 + BLK - 1) / BLK, BLK, 0, stream>>>(
      Z3, cl_start, cl_deg, cl_src, Z3, NC);
  hipMemsetAsync(out, 0, (size_t)NG * 256 * 4, stream);
  k_gemm_mfma<192, 4, 256, false, false, false, true>
      <<<dim3((NC + 127) / 128, 4), BLK, 0, stream>>>(
          Z3, wfm, bm, nullptr, nullptr, nullptr, 0, 0, yb, out, nullptr, NC);
}

// Round 24
// 310.276 us; speedup vs baseline: 1.0086x; 1.0086x over previous
//
#include <hip/hip_runtime.h>

// ---------------------------------------------------------------------------
// GNN compound encoder, MI355X (gfx950) — round 24
// vs round 23 (known-good 313us): ONE safe change — edge loops in both
// gathers manually unrolled by 2 (issue 2 srcl + 10/12 row loads before
// accumulating; a-rows then b-rows sequential adds -> deterministic, same
// class of reshape as round 21 which passed cleanly). gather_h1 is
// latency-serialized (42us vs 16us issue floor / 14us BW floor) at
// grid-limited occupancy; 2x MLP per thread attacks exactly that.
// VGPR ~52 -> ~100 is free (grid-limited, not register-limited).
// Everything else byte-identical to round 23.
// ---------------------------------------------------------------------------

#define NN 100000
#define NE 800000
#define NC 20000
#define NGE 320000
#define NG 256

typedef __attribute__((ext_vector_type(8))) short bf16x8;
typedef __attribute__((ext_vector_type(4))) float f32x4;

__device__ __forceinline__ ushort f2bf(float x) {  // RNE f32 -> bf16
  unsigned u = __float_as_uint(x);
  u = (u + 0x7FFFu + ((u >> 16) & 1u)) >> 16;
  return (ushort)u;
}
__device__ __forceinline__ float bf2f(ushort h) {
  return __uint_as_float(((unsigned)h) << 16);
}
__device__ __forceinline__ float bflo(unsigned w) {
  return __uint_as_float(w << 16);
}
__device__ __forceinline__ float bfhi(unsigned w) {
  return __uint_as_float(w & 0xFFFF0000u);
}

// --------------------------- CSR build -------------------------------------
__global__ void k_count(const int* __restrict__ ei, int nE,
                        int* __restrict__ deg) {
  for (int e = blockIdx.x * blockDim.x + threadIdx.x; e < nE;
       e += gridDim.x * blockDim.x)
    atomicAdd(&deg[ei[nE + e]], 1);
}

__global__ __launch_bounds__(256) void k_scan_block(
    const int* __restrict__ deg, int n, int* __restrict__ start,
    int* __restrict__ bsum) {
  __shared__ int sh[256];
  int base = blockIdx.x * 1024 + threadIdx.x * 4;
  int v0 = (base + 0 < n) ? deg[base + 0] : 0;
  int v1 = (base + 1 < n) ? deg[base + 1] : 0;
  int v2 = (base + 2 < n) ? deg[base + 2] : 0;
  int v3 = (base + 3 < n) ? deg[base + 3] : 0;
  sh[threadIdx.x] = v0 + v1 + v2 + v3;
  __syncthreads();
  for (int off = 1; off < 256; off <<= 1) {
    int t = (threadIdx.x >= off) ? sh[threadIdx.x - off] : 0;
    __syncthreads();
    sh[threadIdx.x] += t;
    __syncthreads();
  }
  int run = (threadIdx.x == 0) ? 0 : sh[threadIdx.x - 1];
  if (base + 0 < n) start[base + 0] = run;
  run += v0;
  if (base + 1 < n) start[base + 1] = run;
  run += v1;
  if (base + 2 < n) start[base + 2] = run;
  run += v2;
  if (base + 3 < n) start[base + 3] = run;
  if (threadIdx.x == 255) bsum[blockIdx.x] = sh[255];
}

__global__ void k_scan_mid(int* __restrict__ bsum, int nb) {
  if (blockIdx.x == 0 && threadIdx.x == 0) {
    int run = 0;
    for (int i = 0; i < nb; ++i) {
      int t = bsum[i];
      bsum[i] = run;
      run += t;
    }
  }
}

__global__ void k_scan_add(int* __restrict__ start, const int* __restrict__ bsum,
                           int n) {
  int i = blockIdx.x * blockDim.x + threadIdx.x;
  if (i < n) start[i] += bsum[i >> 10];
}

// ---- XCD-range-partitioned fill: block (r,g) commits targets in range r ---
__global__ void k_fill2(const int* __restrict__ ei, int nE,
                        const int* __restrict__ start, int* __restrict__ cur,
                        int* __restrict__ dst, int n) {
  int r = blockIdx.x & 7;
  int g = blockIdx.x >> 3;
  int G = gridDim.x >> 3;
  int chunk = (nE + G - 1) / G;
  int e0 = g * chunk;
  int e1 = e0 + chunk; if (e1 > nE) e1 = nE;
  for (int e = e0 + threadIdx.x; e < e1; e += blockDim.x) {
    int t = ei[nE + e];
    if ((t * 8) / n == r) {
      int slot = start[t] + atomicAdd(&cur[t], 1);
      dst[slot] = ei[e];
    }
  }
}

// ---- conv1 tables: M1t[f][v] f32 = W1a@emb^T transposed; T1[v][f] f32 -----
__global__ void k_prep1(const float* __restrict__ w1,
                        const float* __restrict__ b1,
                        const float* __restrict__ emb,
                        float* __restrict__ M1t, float* __restrict__ T1) {
  int idx = blockIdx.x * 256 + threadIdx.x;
  if (idx < 128 * 80) {
    int v = idx / 80, f = idx - v * 80;
    const float* er = emb + (size_t)v * 64;
    const float* wa = w1 + (size_t)f * 128;
    const float* wb = wa + 64;
    float sa = 0.f, sb = b1[f];
    for (int k = 0; k < 64; ++k) {
      sa = fmaf(wa[k], er[k], sa);
      sb = fmaf(wb[k], er[k], sb);
    }
    T1[idx] = sb;
    M1t[(size_t)f * 128 + v] = sa;
  }
}

// ---- adjusted bias: badj[f] = b[f] + sum_k W[f][D1+k]*shift[k] ------------
template <int F, int K, int D1>
__global__ void k_badj(const float* __restrict__ W, const float* __restrict__ b,
                       const float* __restrict__ sc, float* __restrict__ badj) {
  int f = blockIdx.x * blockDim.x + threadIdx.x;
  if (f < F) {
    float s = b[f];
    for (int k = 0; k < K - D1; ++k)
      s += W[(size_t)f * K + D1 + k] * sc[(K - D1) + k];
    badj[f] = s;
  }
}

// -------- W -> fragment-ordered bf16 (optional BN-scale fold k>=D1) --------
template <int KB, int F, int WS, int D1, bool AFFW>
__global__ void k_wfrag(const float* __restrict__ W, const float* __restrict__ scW,
                        ushort* __restrict__ WF) {
  int idx = blockIdx.x * blockDim.x + threadIdx.x;
  constexpr int NFT = F / 16;
  int total = (KB / 32) * NFT * 64;
  if (idx >= total) return;
  int lane = idx & 63, frag = idx >> 6;
  int ftile = frag % NFT, ktile = frag / NFT;
  int f = ftile * 16 + (lane & 15);
  int k0 = ktile * 32 + ((lane >> 4) << 3);
  ushort v[8];
#pragma unroll
  for (int j = 0; j < 8; ++j) {
    int k = k0 + j;
    float w = W[(size_t)f * WS + k];
    if (AFFW && k >= D1) w *= scW[k - D1];
    v[j] = f2bf(w);
  }
  ushort* p = WF + (size_t)idx * 8;
  *reinterpret_cast<ushort4*>(p) = make_ushort4(v[0], v[1], v[2], v[3]);
  *reinterpret_cast<ushort4*>(p + 4) = make_ushort4(v[4], v[5], v[6], v[7]);
}

// ---- atom-count rows: Z1c[nd][128] bf16, counts of neighbor atom ids ------
__global__ __launch_bounds__(256) void k_counts(
    const int* __restrict__ x, const int* __restrict__ start,
    const int* __restrict__ deg, const int* __restrict__ srcl,
    ushort* __restrict__ Z1c, int n) {
  __shared__ unsigned cnt[64][128];
  const int t = threadIdx.x;
  const int nd0 = blockIdx.x * 64;
  for (int i = t; i < 8192; i += 256)
    reinterpret_cast<unsigned*>(cnt)[i] = 0u;
  __syncthreads();
  const int ndl = t >> 2;        // 0..63
  const int j0 = t & 3;
  const int nd = nd0 + ndl;
  if (nd < n) {
    int s0 = start[nd], dg = deg[nd];
    for (int j = j0; j < dg; j += 4) {
      int v = x[srcl[s0 + j]];
      atomicAdd(&cnt[ndl][v], 1u);
    }
  }
  __syncthreads();
  for (int i = t; i < 4096; i += 256) {
    int ndw = i >> 6, vp = i & 63;
    unsigned lo = f2bf((float)cnt[ndw][2 * vp]);
    unsigned hi = f2bf((float)cnt[ndw][2 * vp + 1]);
    int g = nd0 + ndw;
    if (g < n)
      reinterpret_cast<unsigned*>(Z1c + (size_t)g * 128)[vp] = lo | (hi << 16);
  }
}

// -------- conv2 gather: 2 threads/node, 40 feats, edge loop unrolled x2 ----
__global__ __launch_bounds__(256) void k_gather_h1_bf(
    const ushort* __restrict__ Z2r, const int* __restrict__ start,
    const int* __restrict__ deg, const int* __restrict__ srcl,
    const float* __restrict__ sc, ushort* __restrict__ Z2w, int n) {
  int idx = blockIdx.x * blockDim.x + threadIdx.x;
  int nd = idx >> 1, half = idx & 1;
  if (nd >= n) return;
  const int f0 = half * 40;
  float acc[40];
#pragma unroll
  for (int i = 0; i < 40; ++i) acc[i] = 0.f;
  int s0 = start[nd], dg = deg[nd];
  int j = 0;
  for (; j + 2 <= dg; j += 2) {
    int sA = srcl[s0 + j];
    int sB = srcl[s0 + j + 1];
    const uint4* ra = reinterpret_cast<const uint4*>(
        Z2r + (size_t)sA * 160 + 80 + f0);
    const uint4* rb = reinterpret_cast<const uint4*>(
        Z2r + (size_t)sB * 160 + 80 + f0);
    uint4 wa[5], wb[5];
#pragma unroll
    for (int q = 0; q < 5; ++q) wa[q] = ra[q];
#pragma unroll
    for (int q = 0; q < 5; ++q) wb[q] = rb[q];
#pragma unroll
    for (int q = 0; q < 5; ++q) {
      acc[8 * q + 0] += bflo(wa[q].x); acc[8 * q + 1] += bfhi(wa[q].x);
      acc[8 * q + 2] += bflo(wa[q].y); acc[8 * q + 3] += bfhi(wa[q].y);
      acc[8 * q + 4] += bflo(wa[q].z); acc[8 * q + 5] += bfhi(wa[q].z);
      acc[8 * q + 6] += bflo(wa[q].w); acc[8 * q + 7] += bfhi(wa[q].w);
    }
#pragma unroll
    for (int q = 0; q < 5; ++q) {
      acc[8 * q + 0] += bflo(wb[q].x); acc[8 * q + 1] += bfhi(wb[q].x);
      acc[8 * q + 2] += bflo(wb[q].y); acc[8 * q + 3] += bfhi(wb[q].y);
      acc[8 * q + 4] += bflo(wb[q].z); acc[8 * q + 5] += bfhi(wb[q].z);
      acc[8 * q + 6] += bflo(wb[q].w); acc[8 * q + 7] += bfhi(wb[q].w);
    }
  }
  if (j < dg) {
    int s = srcl[s0 + j];
    const uint4* rp = reinterpret_cast<const uint4*>(
        Z2r + (size_t)s * 160 + 80 + f0);
#pragma unroll
    for (int q = 0; q < 5; ++q) {
      uint4 w = rp[q];
      acc[8 * q + 0] += bflo(w.x); acc[8 * q + 1] += bfhi(w.x);
      acc[8 * q + 2] += bflo(w.y); acc[8 * q + 3] += bfhi(w.y);
      acc[8 * q + 4] += bflo(w.z); acc[8 * q + 5] += bfhi(w.z);
      acc[8 * q + 6] += bflo(w.w); acc[8 * q + 7] += bfhi(w.w);
    }
  }
  float fd = (float)dg;
  uint4* op = reinterpret_cast<uint4*>(Z2w + (size_t)nd * 160 + f0);
#pragma unroll
  for (int q = 0; q < 5; ++q) {
    unsigned pk[4];
#pragma unroll
    for (int p = 0; p < 4; ++p) {
      int f = f0 + 8 * q + 2 * p;
      float v0 = fmaf(acc[8 * q + 2 * p + 0], sc[f + 0], fd * sc[80 + f + 0]);
      float v1 = fmaf(acc[8 * q + 2 * p + 1], sc[f + 1], fd * sc[80 + f + 1]);
      pk[p] = (unsigned)f2bf(v0) | ((unsigned)f2bf(v1) << 16);
    }
    op[q] = make_uint4(pk[0], pk[1], pk[2], pk[3]);
  }
}

// -------- cluster gather: 2 threads/cluster, 48 feats, unrolled x2 ---------
__global__ __launch_bounds__(256) void k_gather_y_bf(
    const ushort* __restrict__ Z3r, const int* __restrict__ start,
    const int* __restrict__ deg, const int* __restrict__ srcl,
    ushort* __restrict__ Z3w, int n) {
  int idx = blockIdx.x * blockDim.x + threadIdx.x;
  int c = idx >> 1, half = idx & 1;
  if (c >= n) return;
  const int f0 = half * 48;
  float acc[48];
#pragma unroll
  for (int i = 0; i < 48; ++i) acc[i] = 0.f;
  int s0 = start[c], dg = deg[c];
  int j = 0;
  for (; j + 2 <= dg; j += 2) {
    int sA = srcl[s0 + j];
    int sB = srcl[s0 + j + 1];
    const uint4* ra = reinterpret_cast<const uint4*>(
        Z3r + (size_t)sA * 192 + 96 + f0);
    const uint4* rb = reinterpret_cast<const uint4*>(
        Z3r + (size_t)sB * 192 + 96 + f0);
    uint4 wa[6], wb[6];
#pragma unroll
    for (int q = 0; q < 6; ++q) wa[q] = ra[q];
#pragma unroll
    for (int q = 0; q < 6; ++q) wb[q] = rb[q];
#pragma unroll
    for (int q = 0; q < 6; ++q) {
      acc[8 * q + 0] += bflo(wa[q].x); acc[8 * q + 1] += bfhi(wa[q].x);
      acc[8 * q + 2] += bflo(wa[q].y); acc[8 * q + 3] += bfhi(wa[q].y);
      acc[8 * q + 4] += bflo(wa[q].z); acc[8 * q + 5] += bfhi(wa[q].z);
      acc[8 * q + 6] += bflo(wa[q].w); acc[8 * q + 7] += bfhi(wa[q].w);
    }
#pragma unroll
    for (int q = 0; q < 6; ++q) {
      acc[8 * q + 0] += bflo(wb[q].x); acc[8 * q + 1] += bfhi(wb[q].x);
      acc[8 * q + 2] += bflo(wb[q].y); acc[8 * q + 3] += bfhi(wb[q].y);
      acc[8 * q + 4] += bflo(wb[q].z); acc[8 * q + 5] += bfhi(wb[q].z);
      acc[8 * q + 6] += bflo(wb[q].w); acc[8 * q + 7] += bfhi(wb[q].w);
    }
  }
  if (j < dg) {
    int s = srcl[s0 + j];
    const uint4* rp = reinterpret_cast<const uint4*>(
        Z3r + (size_t)s * 192 + 96 + f0);
#pragma unroll
    for (int q = 0; q < 6; ++q) {
      uint4 w = rp[q];
      acc[8 * q + 0] += bflo(w.x); acc[8 * q + 1] += bfhi(w.x);
      acc[8 * q + 2] += bflo(w.y); acc[8 * q + 3] += bfhi(w.y);
      acc[8 * q + 4] += bflo(w.z); acc[8 * q + 5] += bfhi(w.z);
      acc[8 * q + 6] += bflo(w.w); acc[8 * q + 7] += bfhi(w.w);
    }
  }
  uint4* op = reinterpret_cast<uint4*>(Z3w + (size_t)c * 192 + f0);
#pragma unroll
  for (int q = 0; q < 6; ++q) {
    unsigned pk[4];
#pragma unroll
    for (int p = 0; p < 4; ++p) {
      pk[p] = (unsigned)f2bf(acc[8 * q + 2 * p + 0]) |
              ((unsigned)f2bf(acc[8 * q + 2 * p + 1]) << 16);
    }
    op[q] = make_uint4(pk[0], pk[1], pk[2], pk[3]);
  }
}

// ---- cluster max (5 rows, bf16 in) + BN2 affine (scale>0) -> Z3 y-half ----
__global__ void k_cluster_max_bf(const ushort* __restrict__ h2,
                                 const float* __restrict__ sc,
                                 ushort* __restrict__ Z3, int C) {
  int total = C * 96;
  for (int idx = blockIdx.x * blockDim.x + threadIdx.x; idx < total;
       idx += gridDim.x * blockDim.x) {
    int c = idx / 96;
    int d = idx - c * 96;
    const ushort* p = h2 + (size_t)(c * 5) * 96 + d;
    float m = bf2f(p[0]);
    m = fmaxf(m, bf2f(p[96]));
    m = fmaxf(m, bf2f(p[192]));
    m = fmaxf(m, bf2f(p[288]));
    m = fmaxf(m, bf2f(p[384]));
    m = fmaf(m, sc[d], sc[96 + d]);  // scale>0: affine commutes with max
    Z3[(size_t)c * 192 + 96 + d] = f2bf(m);
  }
}

__global__ void k_ybatch(const int* __restrict__ batch, int* __restrict__ yb,
                         int C) {
  for (int c = blockIdx.x * blockDim.x + threadIdx.x; c < C;
       c += gridDim.x * blockDim.x) {
    int m = batch[c * 5];
    m = max(m, batch[c * 5 + 1]);
    m = max(m, batch[c * 5 + 2]);
    m = max(m, batch[c * 5 + 3]);
    m = max(m, batch[c * 5 + 4]);
    yb[c] = m;
  }
}

// ---- BN partial reduce + finalize: one block PER FEATURE ------------------
template <int D>
__global__ __launch_bounds__(256) void k_bn_reduce_final(
    const float* __restrict__ sp, int nblk, const float* __restrict__ g,
    const float* __restrict__ be, int n, float* __restrict__ sc) {
  constexpr int TD = 2 * D;
  __shared__ double rs[256], rq[256];
  const int d = blockIdx.x;
  const int t = threadIdx.x;
  double s = 0.0, q = 0.0;
  for (int b = t; b < nblk; b += 256) {
    s += (double)sp[(size_t)b * TD + d];
    q += (double)sp[(size_t)b * TD + D + d];
  }
  rs[t] = s;
  rq[t] = q;
  __syncthreads();
  for (int off = 128; off > 0; off >>= 1) {
    if (t < off) {
      rs[t] += rs[t + off];
      rq[t] += rq[t + off];
    }
    __syncthreads();
  }
  if (t == 0) {
    double mean = rs[0] / n;
    double var = rq[0] / n - mean * mean;
    float scale = g[d] * rsqrtf((float)var + 1e-5f);
    sc[d] = scale;
    sc[D + d] = be[d] - (float)mean * scale;
  }
}

// ------------------- MFMA GEMM epilogue (one 16-row tile) ------------------
template <int NT, int FGLOB, bool T1M, bool STATS, bool OUTBF, bool GMAX>
__device__ __forceinline__ void epilogue(
    const f32x4 (&acc)[NT], int r0base, int lane, int fbase, int rows,
    const float* __restrict__ bias, const int* __restrict__ xid,
    const float* __restrict__ t1, ushort* __restrict__ outBF, int ostride,
    int ooff, const int* __restrict__ yb, int g_base, unsigned* gred,
    float* sred) {
  const int r0 = r0base + ((lane >> 4) << 2);
  bool val[4];
  int gb[4], xv[4];
#pragma unroll
  for (int r = 0; r < 4; ++r) {
    int g = r0 + r;
    val[r] = g < rows;
    if (GMAX) gb[r] = yb[val[r] ? g : 0];
    if (T1M) xv[r] = xid[val[r] ? g : 0];
  }
#pragma unroll
  for (int n = 0; n < NT; ++n) {
    const int fl = n * 16 + (lane & 15);
    const int f = fbase + fl;
    float bb = T1M ? 0.f : bias[f];
    float s = 0.f, q = 0.f;
#pragma unroll
    for (int r = 0; r < 4; ++r) {
      if (val[r]) {
        float v = acc[n][r] +
                  (T1M ? t1[(size_t)xv[r] * FGLOB + f] : bb);
        v = v > 0.f ? v : 0.f;
        int g = r0 + r;
        if (OUTBF) outBF[(size_t)g * ostride + ooff + f] = f2bf(v);
        if (GMAX) {
          if (v > 0.f)
            atomicMax(&gred[(gb[r] - g_base) * (NT * 16) + fl],
                      __float_as_uint(v));
        }
        if (STATS) {
          s += v;
          q += v * v;
        }
      }
    }
    if (STATS) {
      s += __shfl_xor(s, 16); q += __shfl_xor(q, 16);
      s += __shfl_xor(s, 32); q += __shfl_xor(q, 32);
      if (lane < 16) {
        atomicAdd(&sred[fl], s);
        atomicAdd(&sred[FGLOB + fl], q);
      }
    }
  }
}

// ------------------- MFMA GEMM on bf16 row-major Z -------------------------
// 128 rows/block: 4 waves x 2 tiles of 16 rows (+0 / +64). Layouts per r12.
template <int KB, int NT, int FGLOB, bool T1M, bool STATS, bool OUTBF,
          bool GMAX>
__global__ __launch_bounds__(256) void k_gemm_mfma(
    const ushort* __restrict__ Z, const ushort* __restrict__ WF,
    const float* __restrict__ bias, const int* __restrict__ xid,
    const float* __restrict__ t1, ushort* __restrict__ outBF, int ostride,
    int ooff, const int* __restrict__ yb, float* __restrict__ gout,
    float* __restrict__ stpart, int rows) {
  constexpr int KSTEPS = KB / 32;
  constexpr int NFT = FGLOB / 16;
  const int t = threadIdx.x;
  const int lane = t & 63;
  const int wv = t >> 6;
  const int rowA = blockIdx.x * 128 + wv * 16;
  const int rowB = rowA + 64;
  const int fbase = blockIdx.y * (NT * 16);
  const int ft0 = fbase >> 4;

  __shared__ float sred[STATS ? 2 * FGLOB : 1];
  __shared__ unsigned gred[GMAX ? 4 * NT * 16 : 1];
  if (STATS)
    for (int i = t; i < 2 * FGLOB; i += 256) sred[i] = 0.f;
  if (GMAX)
    for (int i = t; i < 4 * NT * 16; i += 256) gred[i] = 0u;
  if (STATS || GMAX) __syncthreads();

  int arA = rowA + (lane & 15); if (arA >= rows) arA = rows - 1;
  int arB = rowB + (lane & 15); if (arB >= rows) arB = rows - 1;
  const ushort* apA = Z + (size_t)arA * KB + ((lane >> 4) << 3);
  const ushort* apB = Z + (size_t)arB * KB + ((lane >> 4) << 3);

  f32x4 accA[NT], accB[NT];
#pragma unroll
  for (int n = 0; n < NT; ++n) {
    accA[n] = (f32x4){0.f, 0.f, 0.f, 0.f};
    accB[n] = (f32x4){0.f, 0.f, 0.f, 0.f};
  }

#pragma unroll
  for (int ks = 0; ks < KSTEPS; ++ks) {
    bf16x8 afA = *reinterpret_cast<const bf16x8*>(apA + ks * 32);
    bf16x8 afB = *reinterpret_cast<const bf16x8*>(apB + ks * 32);
#pragma unroll
    for (int n = 0; n < NT; ++n) {
      bf16x8 bf = *reinterpret_cast<const bf16x8*>(
          WF + (((size_t)((ks * NFT + ft0 + n) * 64 + lane)) << 3));
      accA[n] = __builtin_amdgcn_mfma_f32_16x16x32_bf16(afA, bf, accA[n], 0, 0, 0);
      accB[n] = __builtin_amdgcn_mfma_f32_16x16x32_bf16(afB, bf, accB[n], 0, 0, 0);
    }
  }

  int g_base = 0, g_last = 0;
  if (GMAX) {
    int cb = blockIdx.x * 128;       if (cb >= rows) cb = rows - 1;
    int ce = blockIdx.x * 128 + 127; if (ce >= rows) ce = rows - 1;
    g_base = yb[cb];
    g_last = yb[ce];
  }

  epilogue<NT, FGLOB, T1M, STATS, OUTBF, GMAX>(
      accA, rowA, lane, fbase, rows, bias, xid, t1, outBF, ostride, ooff, yb,
      g_base, gred, sred);
  epilogue<NT, FGLOB, T1M, STATS, OUTBF, GMAX>(
      accB, rowB, lane, fbase, rows, bias, xid, t1, outBF, ostride, ooff, yb,
      g_base, gred, sred);

  if (STATS) {
    __syncthreads();
    for (int i = t; i < 2 * FGLOB; i += 256)
      stpart[(size_t)blockIdx.x * (2 * FGLOB) + i] = sred[i];
  }
  if (GMAX) {
    __syncthreads();
    for (int i = t; i < 4 * NT * 16; i += 256) {
      int s = i / (NT * 16), fl = i - s * (NT * 16);
      if (g_base + s <= g_last) {
        unsigned v = gred[i];
        if (v)
          atomicMax((unsigned*)&gout[(size_t)(g_base + s) * 256 + fbase + fl],
                    v);
      }
    }
  }
}

// ---------------------------------------------------------------------------
extern "C" void kernel_launch(void* const* d_in, const int* in_sizes, int n_in,
                              void* d_out, int out_size, void* d_ws,
                              size_t ws_size, hipStream_t stream) {
  const int* x = (const int*)d_in[0];
  const int* ei = (const int*)d_in[1];          // [2][NE]
  const int* batch = (const int*)d_in[2];
  // d_in[3] = cluster_index (contiguous arange//5; structure used directly)
  const int* gei = (const int*)d_in[4];         // [2][NGE]
  const float* emb = (const float*)d_in[5];
  const float* w1 = (const float*)d_in[6];
  const float* b1 = (const float*)d_in[7];
  const float* g1 = (const float*)d_in[8];
  const float* be1 = (const float*)d_in[9];
  const float* w2 = (const float*)d_in[10];
  const float* b2 = (const float*)d_in[11];
  const float* g2 = (const float*)d_in[12];
  const float* be2 = (const float*)d_in[13];
  const float* wm = (const float*)d_in[14];
  const float* bm = (const float*)d_in[15];
  float* out = (float*)d_out;

  // ---- workspace overlay -----------------------------------------------
  ushort* Z2 = (ushort*)d_ws;               // [100032][160] (0-79 agg2, 80-159 h1)
  ushort* Z3 = Z2 + (size_t)100032 * 160;   // [20032][192]  (0-95 aggc, 96-191 y)
  ushort* h2b = Z3 + (size_t)20032 * 192;   // [100032][96]  bf16 h2
  ushort* Z1c = h2b + (size_t)100032 * 96;  // [100032][128] bf16 atom counts
  ushort* wf1 = Z1c + (size_t)100032 * 128; // 4*5*64*8 = 10240
  ushort* wf2 = wf1 + 10240;                // 15360
  ushort* wfm = wf2 + 15360;                // 49152
  float* M1t = (float*)(wfm + 49152);       // [80][128] f32
  float* T1v = M1t + 10240;                 // [128][80] f32
  float* badj2 = T1v + 10240;               // 96 (pad 128)
  float* sc1 = badj2 + 128;                 // 160 (pad 192)
  float* sc2 = sc1 + 192;                   // 192
  float* stpart = sc2 + 192;                // 1024*192 floats
  int* ip = (int*)(stpart + 196608);
  int* nd_deg = ip;            ip += NN;
  int* nd_start = ip;          ip += NN;
  int* nd_cur = ip;            ip += NN;
  int* nd_src = ip;            ip += NE;
  int* cl_deg = ip;            ip += NC;
  int* cl_start = ip;          ip += NC;
  int* cl_cur = ip;            ip += NC;
  int* cl_src = ip;            ip += NGE;
  int* yb = ip;                ip += NC;
  int* bsum = ip;              ip += 128;

  const int BLK = 256;
  const int GB = (NN + 127) / 128;          // 782 GEMM blocks (node layers)
  const int CB = (NN + 63) / 64;            // 1563 counts blocks

  // ---- node-graph CSR (int slots: src)
  hipMemsetAsync(nd_deg, 0, NN * 4, stream);
  hipMemsetAsync(nd_cur, 0, NN * 4, stream);
  k_count<<<1024, BLK, 0, stream>>>(ei, NE, nd_deg);
  k_scan_block<<<(NN + 1023) / 1024, BLK, 0, stream>>>(nd_deg, NN, nd_start, bsum);
  k_scan_mid<<<1, 64, 0, stream>>>(bsum, (NN + 1023) / 1024);
  k_scan_add<<<(NN + 255) / 256, BLK, 0, stream>>>(nd_start, bsum, NN);
  k_fill2<<<1024, BLK, 0, stream>>>(ei, NE, nd_start, nd_cur, nd_src, NN);

  // ---- parameter prep: M1t/T1 tables, conv1+final W fragments
  k_prep1<<<40, BLK, 0, stream>>>(w1, b1, emb, M1t, T1v);
  k_wfrag<128, 80, 128, 128, false><<<5, BLK, 0, stream>>>(M1t, nullptr, wf1);
  k_wfrag<192, 256, 192, 96, false><<<24, BLK, 0, stream>>>(wm, nullptr, wfm);

  // ---- conv1: atom-count rows -> MFMA GEMM (T1 base, stats, h1->Z2 strided)
  k_counts<<<CB, BLK, 0, stream>>>(x, nd_start, nd_deg, nd_src, Z1c, NN);
  k_gemm_mfma<128, 5, 80, true, true, true, false>
      <<<dim3(GB, 1), BLK, 0, stream>>>(
          Z1c, wf1, nullptr, x, T1v, Z2, 160, 80, nullptr, nullptr, stpart,
          NN);
  k_bn_reduce_final<80><<<80, 256, 0, stream>>>(stpart, GB, g1, be1, NN, sc1);
  k_badj<96, 160, 80><<<1, 128, 0, stream>>>(w2, b2, sc1, badj2);
  k_wfrag<160, 96, 160, 80, true><<<8, BLK, 0, stream>>>(w2, sc1, wf2);

  // ---- conv2: gather h1 (2 thr/node, unrolled, affine fold) -> Z2 0-79;
  //      MFMA GEMM -> h2 bf16
  k_gather_h1_bf<<<(NN * 2 + BLK - 1) / BLK, BLK, 0, stream>>>(
      Z2, nd_start, nd_deg, nd_src, sc1, Z2, NN);
  k_gemm_mfma<160, 6, 96, false, true, true, false>
      <<<dim3(GB, 1), BLK, 0, stream>>>(
          Z2, wf2, badj2, nullptr, nullptr, h2b, 96, 0, nullptr, nullptr,
          stpart, NN);
  k_bn_reduce_final<96><<<96, 256, 0, stream>>>(stpart, GB, g2, be2, NN, sc2);

  // ---- cluster pooling: max over 5 rows (bf16) + BN2 affine -> Z3 y-half
  k_cluster_max_bf<<<2048, BLK, 0, stream>>>(h2b, sc2, Z3, NC);
  k_ybatch<<<(NC + BLK - 1) / BLK, BLK, 0, stream>>>(batch, yb, NC);

  // ---- cluster-graph CSR (int slots)
  hipMemsetAsync(cl_deg, 0, NC * 4, stream);
  hipMemsetAsync(cl_cur, 0, NC * 4, stream);
  k_count<<<512, BLK, 0, stream>>>(gei, NGE, cl_deg);
  k_scan_block<<<(NC + 1023) / 1024, BLK, 0, stream>>>(cl_deg, NC, cl_start, bsum);
  k_scan_mid<<<1, 64, 0, stream>>>(bsum, (NC + 1023) / 1024);
  k_scan_add<<<(NC + 255) / 256, BLK, 0, stream>>>(cl_start, bsum, NC);
  k_fill2<<<512, BLK, 0, stream>>>(gei, NGE, cl_start, cl_cur, cl_src, NC);

  // ---- final: gather y (2 thr/cluster, unrolled) -> Z3 cols 0-95;
  //      MFMA GEMM + fused graph-max
  k_gather_y_bf<<<(NC * 2 + BLK - 1) / BLK, BLK, 0, stream>>>(
      Z3, cl_start, cl_deg, cl_src, Z3, NC);
  hipMemsetAsync(out, 0, (size_t)NG * 256 * 4, stream);
  k_gemm_mfma<192, 4, 256, false, false, false, true>
      <<<dim3((NC + 127) / 128, 4), BLK, 0, stream>>>(
          Z3, wfm, bm, nullptr, nullptr, nullptr, 0, 0, yb, out, nullptr, NC);
}